// Round 13
// baseline (315.582 us; speedup 1.0000x reference)
//
#include <hip/hip_runtime.h>
#include <cstdint>
#include <cstddef>

// PCFG inside algorithm. B=8, n=28, NT=32, T=64, ST=96.
// Persistent cooperative kernel v5 -- flagless, self-announcing partials.
// Grid = B*12 blocks, 1024 threads. ch0-7 = TNT role (TT at w==1, then
// TN ch0-3 / NT ch4-7, 512 pair-cols each, E in regs e4[4]); ch8-11 = NN
// role (256 pair-cols each, e4[2]), runs 1.5 rounds ahead (needs only rows
// <= w-2, own normalization M').
// Cross-block traffic = ONLY sign-tagged partials in a 4-slot ring:
//   width w -> slot w&3, tag (w>>2)&1. tag 0: store x (>=0). tag 1: store
//   -x-1 (<=-1). Consumer decodes x = tag ? -q-1 : q and waits until
//   min(x) >= 0. Sentinel -0.5 decodes negative under BOTH tags. Slot
//   ring + parity = mod-8 discrimination; block spread <= 3 => safe.
// M and M' are recomputed locally from the per-block bmax triangle
// (bitwise-identical ascending-k loops) -- no M-row exchange, no flags,
// no store-drain on the critical path. pack_kernel resets slots each
// launch (graph-replay safe).

#define NMAX 28
#define PITCH 12
#define SLOTF 10368   // 12*864 floats per slot

// LDS float offsets
#define O_BW1 0        // 32*30: eB row w-1 [sym][s] (TNT)
#define O_BMX 960      // 28*28: bmax triangle [lvl][pos] (persistent)
#define O_G   1744     // 28*28: TNT rows 0,1 = g0,gw ; NN: g'[k][s]
#define O_MSP 2528     // 32: TNT Mspan (persists into next finalize)
#define O_EMR 2560     // 32: exp(mrule)
#define O_NUM 2592     // ushort numer: 27 spans * 520 (1040B pitch) = 7020 f
#define O_RED 9612     // 16*896 = 14336
// TNT only:
#define O_ELT 23948    // 64*29 elT[t][pos]
// NN only (ELK aliases RED; dead by D):
#define O_ELK 9612     // 8320
#define O_ERK 17932    // 8320
#define O_TRI 26252    // 377*32 = 12064: eB rows 1..26
#define LDSF  38316    // *4 = 153264 B

__device__ __forceinline__ int off32(int w, int n) {
    return (w - 1) * n - (w * (w - 1)) / 2;
}
__device__ __forceinline__ float gload(const float* p) {
    return __hip_atomic_load(p, __ATOMIC_RELAXED, __HIP_MEMORY_SCOPE_AGENT);
}
__device__ __forceinline__ void gstore(float* p, float v) {
    __hip_atomic_store(p, v, __ATOMIC_RELAXED, __HIP_MEMORY_SCOPE_AGENT);
}
__device__ __forceinline__ float dot4acc(float4 m, float4 t, float acc) {
    return fmaf(m.x, t.x, fmaf(m.y, t.y, fmaf(m.z, t.z, fmaf(m.w, t.w, acc))));
}

__global__ __launch_bounds__(256) void mrule_kernel(const float* __restrict__ rule,
                                                    float* __restrict__ mrule) {
    int a = blockIdx.x, b = blockIdx.y, tid = threadIdx.x;
    const float* base = rule + (size_t)(b * 32 + a) * 9216;
    float v = -3.0e38f;
    for (int i = tid; i < 9216; i += 256) v = fmaxf(v, base[i]);
    for (int off = 32; off > 0; off >>= 1) v = fmaxf(v, __shfl_xor(v, off, 64));
    __shared__ float red[4];
    if ((tid & 63) == 0) red[tid >> 6] = v;
    __syncthreads();
    if (tid == 0)
        mrule[b * 32 + a] = fmaxf(fmaxf(red[0], red[1]), fmaxf(red[2], red[3]));
}

__global__ __launch_bounds__(256) void pack_kernel(const float* __restrict__ rule,
                                                   const float* __restrict__ mrule,
                                                   float* __restrict__ E_TT,
                                                   float* __restrict__ E_TN,
                                                   float* __restrict__ E_NT,
                                                   float* __restrict__ E_NN,
                                                   float* __restrict__ part) {
    int b = blockIdx.y, tid = threadIdx.x;
    // reset the 4 partial slots of batch b to sentinel (-0.5: not-ready
    // under both tags). Cached stores; kernel-end flush makes them visible
    // to inside_kernel's uncached loads. Re-runs on every launch (replay-safe).
    {
        const int total = 4 * SLOTF;
        for (int i = blockIdx.x * 256 + tid; i < total; i += 288 * 256)
            part[(size_t)b * total + i] = -0.5f;
    }
    int a = tid & 31;
    int cc = blockIdx.x * 8 + (tid >> 5); // 0..2303
    float mr = mrule[b * 32 + a];
    int l, r;
    float* dst;
    if (cc < 1024) {
        int flat = cc * 4;
        l = 32 + (flat >> 6); r = 32 + (flat & 63);
        dst = E_TT + ((size_t)(b * 1024 + cc) * 32 + a) * 4;
    } else if (cc < 1536) {
        int flat = (cc - 1024) * 4;
        l = 32 + (flat >> 5); r = flat & 31;
        dst = E_TN + ((size_t)(b * 512 + (cc - 1024)) * 32 + a) * 4;
    } else if (cc < 2048) {
        int flat = (cc - 1536) * 4;
        l = flat >> 6; r = 32 + (flat & 63);
        dst = E_NT + ((size_t)(b * 512 + (cc - 1536)) * 32 + a) * 4;
    } else {
        int flat = (cc - 2048) * 4;
        l = flat >> 5; r = flat & 31;
        dst = E_NN + ((size_t)(b * 256 + (cc - 2048)) * 32 + a) * 4;
    }
    const float4 v = *(const float4*)(rule + (((size_t)(b * 32 + a) * 96 + l) * 96 + r));
    float4 o;
    o.x = expf(v.x - mr); o.y = expf(v.y - mr);
    o.z = expf(v.z - mr); o.w = expf(v.w - mr);
    *(float4*)dst = o;
}

// Poll-decode macro body as a function: loads 12 tagged values for element
// `e` of slot pbP, decodes by oddp, spins until first CHp are ready.
__device__ __forceinline__ void poll12(const float* pp, bool oddp, int CHp,
                                       float x[12]) {
    for (;;) {
        #pragma unroll
        for (int c = 0; c < 12; ++c) x[c] = gload(pp + c);
        if (oddp) {
            #pragma unroll
            for (int c = 0; c < 12; ++c) x[c] = -x[c] - 1.0f;
        }
        float mn = fminf(fminf(fminf(x[0], x[1]), fminf(x[2], x[3])),
                         fminf(fminf(x[4], x[5]), fminf(x[6], x[7])));
        if (CHp == 12)
            mn = fminf(mn, fminf(fminf(x[8], x[9]), fminf(x[10], x[11])));
        if (mn >= 0.0f) break;
        __builtin_amdgcn_s_sleep(4);
    }
}

__global__ __launch_bounds__(1024, 4) void inside_kernel(
    const float* __restrict__ unary, const float* __restrict__ mrule,
    const float* __restrict__ E_TT, const float* __restrict__ E_TN,
    const float* __restrict__ E_NT, const float* __restrict__ E_NN,
    float* __restrict__ part, const float* __restrict__ root,
    float* __restrict__ out, int n) {
    extern __shared__ float lds[];
    const int b = blockIdx.x / 12, ch = blockIdx.x % 12;
    const int tid = threadIdx.x;
    const int a = tid & 31, g = tid >> 5;   // g: 0..31
    float* const pbase = part + (size_t)(b * 4) * SLOTF;

    // ---- prologue: E regs, emrule, bmax row 0, elT (TNT only) ----
    float4 e4[4];
    if (ch < 8) {
        const float4* Eq = (const float4*)E_TT + (size_t)b * 32768;
        #pragma unroll
        for (int i = 0; i < 4; ++i)
            e4[i] = Eq[(size_t)(ch * 128 + g * 4 + i) * 32 + a];
    } else {
        const float4* Eq = (const float4*)E_NN + (size_t)b * 8192;
        #pragma unroll
        for (int i = 0; i < 2; ++i)
            e4[i] = Eq[(size_t)((ch - 8) * 64 + g * 2 + i) * 32 + a];
    }
    if (tid < 32) lds[O_EMR + tid] = __expf(mrule[b * 32 + tid]);
    for (int pos = tid >> 6; pos < n; pos += 16) {
        int t = tid & 63;
        float v = unary[((size_t)b * n + pos) * 64 + t];
        float m = v;
        for (int off = 32; off > 0; off >>= 1) m = fmaxf(m, __shfl_xor(m, off, 64));
        if (t == 0) lds[O_BMX + pos] = m;
        if (ch < 8) lds[O_ELT + t * 29 + pos] = __expf(v - m);
    }
    __syncthreads();

    if (ch < 8) {
        // ================= TNT role =================
        for (int w = 1; w < n; ++w) {
            const int S = n - w;
            const bool oddw = ((w >> 2) & 1) != 0;
            float* pbW = pbase + (size_t)(w & 3) * SLOTF;

            // ---- phase A: poll + finalize width w-1 ----
            if (w >= 2) {
                const int wp = w - 1;
                const int CHp = (wp >= 3) ? 12 : 8;
                const bool oddp = ((wp >> 2) & 1) != 0;
                const float* pbP = pbase + (size_t)(wp & 3) * SLOTF;
                if (tid < (S + 1) * 32) {
                    int s = tid >> 5, aa = tid & 31;
                    // local M'(wp) for NN rescale (rows 1..wp-2, all old)
                    float Mp = -3.0e38f;
                    for (int k = 1; k <= wp - 2; ++k)
                        Mp = fmaxf(Mp, lds[O_BMX + k * NMAX + s] +
                                       lds[O_BMX + (wp - 1 - k) * NMAX + s + k + 1]);
                    float x[12];
                    poll12(pbP + (size_t)tid * PITCH, oddp, CHp, x);
                    float tT = (((x[0] + x[1]) + (x[2] + x[3])) +
                                ((x[4] + x[5]) + (x[6] + x[7])));
                    float t = tT;
                    if (CHp == 12) {
                        float tN = (x[8] + x[9]) + (x[10] + x[11]);
                        t = fmaf(__expf(Mp - lds[O_MSP + s]), tN, tT);
                    }
                    float t2 = t * lds[O_EMR + aa];
                    float m2 = t2;
                    for (int off = 16; off > 0; off >>= 1)
                        m2 = fmaxf(m2, __shfl_xor(m2, off, 32));
                    lds[O_BW1 + aa * 30 + s] = t2 / m2;
                    if (aa == 0)
                        lds[O_BMX + wp * NMAX + s] = __logf(m2) + lds[O_MSP + s];
                }
            }
            __syncthreads();

            // ---- phase B: Mspan + g0/gw ----
            if (tid < S) {
                int s = tid;
                float M = -3.0e38f;
                for (int k = 0; k < w; ++k)
                    M = fmaxf(M, lds[O_BMX + k * NMAX + s] +
                                  lds[O_BMX + (w - 1 - k) * NMAX + s + k + 1]);
                lds[O_MSP + s] = M;
                lds[O_G + s] =
                    __expf(lds[O_BMX + s] + lds[O_BMX + (w - 1) * NMAX + s + 1] - M);
                lds[O_G + NMAX + s] =
                    __expf(lds[O_BMX + (w - 1) * NMAX + s] + lds[O_BMX + s + w] - M);
            }
            __syncthreads();

            // ---- phase C: numer (512 cols) -> bf16 LDS ----
            {
                const int cL = tid & 511, sh = tid >> 9;   // sh: 0..1
                const bool tn = (w >= 2) && (ch < 4);
                const int cc = (w == 1) ? ch * 512 + cL
                             : (ch < 4 ? ch * 512 + cL : (ch - 4) * 512 + cL);
                int l, r;
                if (tn) { l = cc >> 5; r = cc & 31; }
                else    { l = cc >> 6; r = cc & 63; }
                unsigned short* np = (unsigned short*)(lds + O_NUM);
                for (int s = sh; s < S; s += 2) {
                    float v;
                    if (w == 1)
                        v = lds[O_ELT + l * 29 + s] * lds[O_ELT + r * 29 + (s + 1)] *
                            lds[O_G + s];
                    else if (tn)
                        v = lds[O_ELT + l * 29 + s] * lds[O_BW1 + r * 30 + (s + 1)] *
                            lds[O_G + s];
                    else
                        v = lds[O_BW1 + l * 30 + s] * lds[O_ELT + r * 29 + (s + w)] *
                            lds[O_G + NMAX + s];
                    unsigned u = __float_as_uint(v);
                    np[s * 520 + cL] = (unsigned short)((u + 0x7fffu + ((u >> 16) & 1u)) >> 16);
                }
            }
            __syncthreads();

            // ---- phase D: contraction (16 cols/thread: 2 uint4 + 16 fma) ----
            {
                const char* nbase = (const char*)(lds + O_NUM);
                const int wv = tid >> 6;
                const bool lowhalf = (tid & 32) == 0;
                for (int s = 0; s < S; ++s) {
                    uint4 u0 = *(const uint4*)(nbase + s * 1040 + g * 32);
                    uint4 u1 = *(const uint4*)(nbase + s * 1040 + g * 32 + 16);
                    float acc = 0.f;
                    #define LO(q) __uint_as_float((q) << 16)
                    #define HI(q) __uint_as_float((q) & 0xffff0000u)
                    acc = fmaf(LO(u0.x), e4[0].x, acc); acc = fmaf(HI(u0.x), e4[0].y, acc);
                    acc = fmaf(LO(u0.y), e4[0].z, acc); acc = fmaf(HI(u0.y), e4[0].w, acc);
                    acc = fmaf(LO(u0.z), e4[1].x, acc); acc = fmaf(HI(u0.z), e4[1].y, acc);
                    acc = fmaf(LO(u0.w), e4[1].z, acc); acc = fmaf(HI(u0.w), e4[1].w, acc);
                    acc = fmaf(LO(u1.x), e4[2].x, acc); acc = fmaf(HI(u1.x), e4[2].y, acc);
                    acc = fmaf(LO(u1.y), e4[2].z, acc); acc = fmaf(HI(u1.y), e4[2].w, acc);
                    acc = fmaf(LO(u1.z), e4[3].x, acc); acc = fmaf(HI(u1.z), e4[3].y, acc);
                    acc = fmaf(LO(u1.w), e4[3].z, acc); acc = fmaf(HI(u1.w), e4[3].w, acc);
                    #undef LO
                    #undef HI
                    acc += __shfl_xor(acc, 32, 64);
                    if (lowhalf) lds[O_RED + wv * 896 + s * 32 + a] = acc;
                }
            }
            __syncthreads();

            // ---- phase E: reduce -> tagged uncached partial stores ----
            if (tid < S * 32) {
                float t = 0.f;
                #pragma unroll
                for (int g2 = 0; g2 < 16; ++g2) t += lds[O_RED + g2 * 896 + tid];
                gstore(&pbW[(size_t)tid * PITCH + ch], oddw ? (-t - 1.0f) : t);
            }
            // no barrier: stores self-announce; next A doesn't touch RED.

            if (w == 1) {
                const float4* Eq = (ch < 4)
                    ? (const float4*)E_TN + (size_t)b * 16384 + (size_t)(ch * 128) * 32
                    : (const float4*)E_NT + (size_t)b * 16384 + (size_t)((ch - 4) * 128) * 32;
                #pragma unroll
                for (int i = 0; i < 4; ++i)
                    e4[i] = Eq[(size_t)(g * 4 + i) * 32 + a];
            }
        }

        // ---- epilogue (ch==0): width n-1, span 0 + root logsumexp ----
        if (ch == 0 && tid < 32) {
            const int wp = n - 1;
            const bool oddp = ((wp >> 2) & 1) != 0;
            const float* pbP = pbase + (size_t)(wp & 3) * SLOTF;
            float Mp = -3.0e38f;
            for (int k = 1; k <= wp - 2; ++k)
                Mp = fmaxf(Mp, lds[O_BMX + k * NMAX + 0] +
                               lds[O_BMX + (wp - 1 - k) * NMAX + k + 1]);
            float x[12];
            poll12(pbP + (size_t)tid * PITCH, oddp, 12, x);
            float tT = (((x[0] + x[1]) + (x[2] + x[3])) +
                        ((x[4] + x[5]) + (x[6] + x[7])));
            float tN = (x[8] + x[9]) + (x[10] + x[11]);
            float t = fmaf(__expf(Mp - lds[O_MSP + 0]), tN, tT);
            float v = __logf(t) + lds[O_MSP + 0] + mrule[b * 32 + tid] + root[b * 32 + tid];
            float m = v;
            for (int off = 16; off > 0; off >>= 1) m = fmaxf(m, __shfl_xor(m, off, 32));
            float e = __expf(v - m);
            for (int off = 16; off > 0; off >>= 1) e += __shfl_xor(e, off, 32);
            if (tid == 0) out[b] = m + __logf(e);
        }
    } else {
        // ================= NN role (1.5 rounds ahead) =================
        for (int w = 3; w < n; ++w) {
            const int S = n - w, Sp2 = S | 1;
            int q4 = (w - 2 + 3) >> 2; if (!(q4 & 1)) ++q4;
            const int K4 = 4 * q4;
            const bool oddw = ((w >> 2) & 1) != 0;
            float* pbW = pbase + (size_t)(w & 3) * SLOTF;

            // ---- A1: poll + finalize width w-2 into TRI + bmax row ----
            {
                const int wf = w - 2;
                const int CHp = (wf >= 3) ? 12 : 8;
                const bool oddp = ((wf >> 2) & 1) != 0;
                const float* pbF = pbase + (size_t)(wf & 3) * SLOTF;
                if (tid < (n - wf) * 32) {
                    int s = tid >> 5, aa = tid & 31;
                    // local M(wf) (ascending k, identical to TNT's B loop)
                    float Mw = -3.0e38f;
                    for (int k = 0; k < wf; ++k)
                        Mw = fmaxf(Mw, lds[O_BMX + k * NMAX + s] +
                                       lds[O_BMX + (wf - 1 - k) * NMAX + s + k + 1]);
                    // local M'(wf) (ascending, identical to TNT's A loop)
                    float Mp = -3.0e38f;
                    for (int k = 1; k <= wf - 2; ++k)
                        Mp = fmaxf(Mp, lds[O_BMX + k * NMAX + s] +
                                       lds[O_BMX + (wf - 1 - k) * NMAX + s + k + 1]);
                    float x[12];
                    poll12(pbF + (size_t)tid * PITCH, oddp, CHp, x);
                    float tT = (((x[0] + x[1]) + (x[2] + x[3])) +
                                ((x[4] + x[5]) + (x[6] + x[7])));
                    float t = tT;
                    if (CHp == 12) {
                        float tN = (x[8] + x[9]) + (x[10] + x[11]);
                        t = fmaf(__expf(Mp - Mw), tN, tT);
                    }
                    float t2 = t * lds[O_EMR + aa];
                    float m2 = t2;
                    for (int off = 16; off > 0; off >>= 1)
                        m2 = fmaxf(m2, __shfl_xor(m2, off, 32));
                    lds[O_TRI + (off32(wf, n) + s) * 32 + aa] = t2 / m2;
                    if (aa == 0) lds[O_BMX + wf * NMAX + s] = __logf(m2) + Mw;
                }
            }
            __syncthreads();

            // ---- A2: M'(w) + g'[k][s] ----
            if (tid < (w - 2) * 32) {
                int k = (tid >> 5) + 1, s = tid & 31;
                if (s < S) {
                    float Mp = -3.0e38f;
                    for (int k2 = 1; k2 <= w - 2; ++k2)
                        Mp = fmaxf(Mp, lds[O_BMX + k2 * NMAX + s] +
                                       lds[O_BMX + (w - 1 - k2) * NMAX + s + k2 + 1]);
                    lds[O_G + k * NMAX + s] =
                        __expf(lds[O_BMX + k * NMAX + s] +
                               lds[O_BMX + (w - 1 - k) * NMAX + s + k + 1] - Mp);
                }
            }
            __syncthreads();

            // ---- A3: k-packed ELK/ERK from TRI (g' folded into ERK) ----
            if (tid < S * 32) {
                int s = tid >> 5, sym = tid & 31;
                int off = (sym * Sp2 + s) * K4;
                for (int kk = 1; kk <= w - 2; ++kk) {
                    lds[O_ELK + off + kk - 1] =
                        lds[O_TRI + (off32(kk, n) + s) * 32 + sym];
                    lds[O_ERK + off + kk - 1] =
                        lds[O_TRI + (off32(w - 1 - kk, n) + s + kk + 1) * 32 + sym] *
                        lds[O_G + kk * NMAX + s];
                }
                for (int k = w - 2; k < K4; ++k) {
                    lds[O_ELK + off + k] = 0.f;
                    lds[O_ERK + off + k] = 0.f;
                }
            }
            __syncthreads();

            // ---- C: numer (256 cols, K4 dot) -> bf16 LDS ----
            {
                const int cL = tid & 255, sh = tid >> 8;
                const int cc = (ch - 8) * 256 + cL;
                const int l = cc >> 5, r = cc & 31;
                unsigned short* np = (unsigned short*)(lds + O_NUM);
                for (int s = sh; s < S; s += 4) {
                    const float* elp = lds + O_ELK + (l * Sp2 + s) * K4;
                    const float* erp = lds + O_ERK + (r * Sp2 + s) * K4;
                    float acc = 0.f;
                    for (int j = 0; j < K4; j += 4)
                        acc = dot4acc(*(const float4*)(elp + j),
                                      *(const float4*)(erp + j), acc);
                    unsigned u = __float_as_uint(acc);
                    np[s * 520 + cL] = (unsigned short)((u + 0x7fffu + ((u >> 16) & 1u)) >> 16);
                }
            }
            __syncthreads();

            // ---- D: contraction (8 cols/thread: 1 uint4 + 8 fma) ----
            {
                const char* nbase = (const char*)(lds + O_NUM);
                const int wv = tid >> 6;
                const bool lowhalf = (tid & 32) == 0;
                for (int s = 0; s < S; ++s) {
                    uint4 u = *(const uint4*)(nbase + s * 1040 + g * 16);
                    float acc = 0.f;
                    #define LO(q) __uint_as_float((q) << 16)
                    #define HI(q) __uint_as_float((q) & 0xffff0000u)
                    acc = fmaf(LO(u.x), e4[0].x, acc); acc = fmaf(HI(u.x), e4[0].y, acc);
                    acc = fmaf(LO(u.y), e4[0].z, acc); acc = fmaf(HI(u.y), e4[0].w, acc);
                    acc = fmaf(LO(u.z), e4[1].x, acc); acc = fmaf(HI(u.z), e4[1].y, acc);
                    acc = fmaf(LO(u.w), e4[1].z, acc); acc = fmaf(HI(u.w), e4[1].w, acc);
                    #undef LO
                    #undef HI
                    acc += __shfl_xor(acc, 32, 64);
                    if (lowhalf) lds[O_RED + wv * 896 + s * 32 + a] = acc;
                }
            }
            __syncthreads();

            // ---- E: reduce -> tagged uncached partial stores ----
            if (tid < S * 32) {
                float t = 0.f;
                #pragma unroll
                for (int g2 = 0; g2 < 16; ++g2) t += lds[O_RED + g2 * 896 + tid];
                gstore(&pbW[(size_t)tid * PITCH + ch], oddw ? (-t - 1.0f) : t);
            }
            __syncthreads();   // protects RED/ELK alias before next A3
        }
    }
}

extern "C" void kernel_launch(void* const* d_in, const int* in_sizes, int n_in,
                              void* d_out, int out_size, void* d_ws, size_t ws_size,
                              hipStream_t stream) {
    const float* unary = (const float*)d_in[0]; // B,n,64
    const float* rule  = (const float*)d_in[1]; // B,32,96,96
    const float* root  = (const float*)d_in[2]; // B,32
    float* out = (float*)d_out;

    const int B = in_sizes[2] / 32;
    int n = in_sizes[0] / (B * 64);

    float* ws = (float*)d_ws;
    float* mrule  = ws;                               // B*32
    float* E_TT   = mrule + (size_t)B * 32;           // B*1024*32*4
    float* E_TN   = E_TT + (size_t)B * 131072;        // B*512*32*4
    float* E_NT   = E_TN + (size_t)B * 65536;         // B*512*32*4
    float* E_NN   = E_NT + (size_t)B * 65536;         // B*256*32*4
    float* part   = E_NN + (size_t)B * 32768;         // B*4*SLOTF

    mrule_kernel<<<dim3(32, B), 256, 0, stream>>>(rule, mrule);
    pack_kernel<<<dim3(288, B), 256, 0, stream>>>(rule, mrule, E_TT, E_TN, E_NT,
                                                  E_NN, part);

    hipFuncSetAttribute((const void*)inside_kernel,
                        hipFuncAttributeMaxDynamicSharedMemorySize, LDSF * 4);

    void* args[] = {
        (void*)&unary, (void*)&mrule,
        (void*)&E_TT, (void*)&E_TN, (void*)&E_NT, (void*)&E_NN,
        (void*)&part, (void*)&root, (void*)&out, (void*)&n
    };
    hipLaunchCooperativeKernel((void*)inside_kernel, dim3(B * 12), dim3(1024),
                               args, LDSF * 4, stream);
}

// Round 14
// 315.059 us; speedup vs baseline: 1.0017x; 1.0017x over previous
//
#include <hip/hip_runtime.h>
#include <cstdint>
#include <cstddef>

// PCFG inside algorithm. B=8, n=28, NT=32, T=64, ST=96.
// v6: width-invariant factor tables + flag-synced persistent kernel.
//   F[r][s][a] = sum_l elT[l][s]*exp(rule[a][32+l][r])      (TN, r in NT)
//   G[l][s'][a] = sum_r elT[r][s']*exp(rule[a][l][32+r])    (NT, l in NT)
//   H[r][s][a] = sum_l elT[l][s]*exp(rule[a][32+l][32+r])   (TT, r in T)
// exp(mrule) folded back => tables are plain exp(rule) (bounded, safe).
// total_TN[s][a] = g0[s]*sum_r BW1[r][s+1]*F[r][s][a]  (8 FMA per block)
// total_NT[s][a] = gw[s]*sum_l BW1[l][s]*G[l][s+w][a]
// Grid B*12 blocks, 1024 thr: ch0-3 TN(8 r's), ch4-7 NT(8 l's) [TT at w==1:
// all 8 own 8 H-slots]; ch8-11 NN (256 pair-cols, E regs, bf16 numer,
// runs 2 rounds ahead with local M' normalization; R13-validated local-M).
// Sync: R12's monotone per-block flags + spin (robust), 4-slot partial ring
// [elem*12+ch]; flags reset in prep each launch. All cross-block data via
// agent-scope (uncached) atomics. Finalize math in shared inline helpers so
// all roles produce bitwise-identical rows.

#define NMAX 28
#define SLOTF 10368   // 864*12
// TNT LDS offsets (floats)
#define T_ELT 0       // 64*29
#define T_BW1 1856    // 32*30
#define T_BMX 2816    // 28*28
#define T_MSP 3600    // 28 (+pad)
#define T_GG  3632    // g0 at +s, gw at +32+s
#define T_HB  3712    // 8*28*32
#define T_FB  10880   // 8*28*32 -> 18048
// NN LDS offsets
#define N_BMX 0       // 784
#define N_GP  784     // 784
#define N_NUM 1568    // 27*132 (ushort pitch 264)
#define N_RED 5132    // 16*896
#define N_ELK 5132    // 8320 (aliases RED; dead by D)
#define N_ERK 13452   // 8320
#define N_TRI 21772   // 377*32
#define LDSF  33836

__device__ __forceinline__ int off32(int w, int n) {
    return (w - 1) * n - (w * (w - 1)) / 2;
}
__device__ __forceinline__ float gload(const float* p) {
    return __hip_atomic_load(p, __ATOMIC_RELAXED, __HIP_MEMORY_SCOPE_AGENT);
}
__device__ __forceinline__ void gstore(float* p, float v) {
    __hip_atomic_store(p, v, __ATOMIC_RELAXED, __HIP_MEMORY_SCOPE_AGENT);
}
__device__ __forceinline__ unsigned gloadu(const unsigned* p) {
    return __hip_atomic_load(p, __ATOMIC_RELAXED, __HIP_MEMORY_SCOPE_AGENT);
}
__device__ __forceinline__ void gstoreu(unsigned* p, unsigned v) {
    __hip_atomic_store(p, v, __ATOMIC_RELAXED, __HIP_MEMORY_SCOPE_AGENT);
}
__device__ __forceinline__ float dot4acc(float4 m, float4 t, float acc) {
    return fmaf(m.x, t.x, fmaf(m.y, t.y, fmaf(m.z, t.z, fmaf(m.w, t.w, acc))));
}
// ---- shared helpers: identical codegen across roles (bitwise consistency) ----
__device__ __forceinline__ float maxM(const float* bmx, int w, int s) {
    float M = -3.0e38f;
    for (int k = 0; k < w; ++k)
        M = fmaxf(M, bmx[k * NMAX + s] + bmx[(w - 1 - k) * NMAX + s + k + 1]);
    return M;
}
__device__ __forceinline__ float maxMp(const float* bmx, int w, int s) {
    float M = -3.0e38f;
    for (int k = 1; k <= w - 2; ++k)
        M = fmaxf(M, bmx[k * NMAX + s] + bmx[(w - 1 - k) * NMAX + s + k + 1]);
    return M;
}
__device__ __forceinline__ float finalize_sum(const float* pp, bool hasNN,
                                              float Mp, float Mw) {
    float x[12];
    #pragma unroll
    for (int c = 0; c < 12; ++c) x[c] = gload(pp + c);
    float tT = (((x[0] + x[1]) + (x[2] + x[3])) + ((x[4] + x[5]) + (x[6] + x[7])));
    float t = tT;
    if (hasNN) {
        float tN = (x[8] + x[9]) + (x[10] + x[11]);
        t = fmaf(__expf(Mp - Mw), tN, tT);
    }
    return t;
}
__device__ __forceinline__ void spin12(const unsigned* f, unsigned tgt, int tid) {
    if (tid < 64) {
        for (;;) {
            unsigned v = (tid < 12) ? gloadu(&f[tid]) : tgt;
            if (__ballot(v < tgt) == 0ull) break;
            __builtin_amdgcn_s_sleep(1);
        }
    }
    __syncthreads();
}

// ---- prep: elT, bmax0, flag init ----
__global__ __launch_bounds__(256) void prep_kernel(const float* __restrict__ unary,
                                                   float* __restrict__ elT_g,
                                                   float* __restrict__ bmax0_g,
                                                   unsigned* __restrict__ flags, int n) {
    int b = blockIdx.x, tid = threadIdx.x;
    if (tid < 12) gstoreu(&flags[b * 32 + tid], (tid >= 8) ? 2u : 0u);
    for (int pos = tid >> 6; pos < n; pos += 4) {
        int t = tid & 63;
        float v = unary[((size_t)(b * n) + pos) * 64 + t];
        float m = v;
        for (int off = 32; off > 0; off >>= 1) m = fmaxf(m, __shfl_xor(m, off, 64));
        elT_g[(size_t)b * 64 * n + t * n + pos] = __expf(v - m);
        if (t == 0) bmax0_g[b * 32 + pos] = m;
    }
}

// ---- pack: per (b,a) block builds exp(rule) slice -> F,G,H,E_NN ----
__global__ __launch_bounds__(256) void pack_kernel(const float* __restrict__ rule,
                                                   const float* __restrict__ elT_g,
                                                   float* __restrict__ H_g,
                                                   float* __restrict__ F_g,
                                                   float* __restrict__ G_g,
                                                   float* __restrict__ E_NN, int n) {
    extern __shared__ float sl[];   // 9216 slice + 64*n elT
    int b = blockIdx.y, aa = blockIdx.x, tid = threadIdx.x;
    const float4* rs4 = (const float4*)(rule + (size_t)(b * 32 + aa) * 9216);
    for (int i = tid; i < 2304; i += 256) {
        float4 v = rs4[i];
        float4 o;
        o.x = __expf(v.x); o.y = __expf(v.y); o.z = __expf(v.z); o.w = __expf(v.w);
        ((float4*)sl)[i] = o;
    }
    for (int i = tid; i < 64 * n; i += 256)
        sl[9216 + i] = elT_g[(size_t)b * 64 * n + i];
    __syncthreads();
    const float* elt = sl + 9216;
    // E_NN quadrant (l<32, r<32), [c4][a][4] layout
    {
        int c4 = tid;
        if (c4 < 256) {
            int flat = c4 * 4, l = flat >> 5, r = flat & 31;
            float4 o = *(const float4*)(sl + l * 96 + r);
            *(float4*)(E_NN + ((size_t)(b * 256 + c4) * 32 + aa) * 4) = o;
        }
    }
    // H[r(64)][s][a]
    for (int i = tid; i < 64 * n; i += 256) {
        int r = i / n, s = i - r * n;
        float acc = 0.f;
        for (int l = 0; l < 64; ++l)
            acc = fmaf(elt[l * n + s], sl[(32 + l) * 96 + 32 + r], acc);
        H_g[((size_t)(b * 64 + r) * n + s) * 32 + aa] = acc;
    }
    // F[r'(32)][s][a]
    for (int i = tid; i < 32 * n; i += 256) {
        int r = i / n, s = i - r * n;
        float acc = 0.f;
        for (int l = 0; l < 64; ++l)
            acc = fmaf(elt[l * n + s], sl[(32 + l) * 96 + r], acc);
        F_g[((size_t)(b * 32 + r) * n + s) * 32 + aa] = acc;
    }
    // G[l'(32)][s'][a]
    for (int i = tid; i < 32 * n; i += 256) {
        int l = i / n, s = i - l * n;
        float acc = 0.f;
        for (int r = 0; r < 64; ++r)
            acc = fmaf(elt[r * n + s], sl[l * 96 + 32 + r], acc);
        G_g[((size_t)(b * 32 + l) * n + s) * 32 + aa] = acc;
    }
}

__global__ __launch_bounds__(1024, 1) void inside_kernel(
    const float* __restrict__ elT_g, const float* __restrict__ bmax0_g,
    const float* __restrict__ H_g, const float* __restrict__ F_g,
    const float* __restrict__ G_g, const float* __restrict__ E_NN,
    float* __restrict__ part, const float* __restrict__ root,
    float* __restrict__ out, unsigned* __restrict__ flags, int n) {
    extern __shared__ float lds[];
    const int b = blockIdx.x / 12, ch = blockIdx.x % 12;
    const int tid = threadIdx.x;
    const int a = tid & 31;
    unsigned* const myflags = flags + b * 32;
    float* const pbase = part + (size_t)(b * 4) * SLOTF;

    if (ch < 8) {
        // ================= TNT role =================
        for (int i = tid; i < 64 * n; i += 1024) {
            int t = i / n, pos = i - t * n;
            lds[T_ELT + t * 29 + pos] = elT_g[(size_t)b * 64 * n + i];
        }
        for (int i = tid; i < 8 * n * 32; i += 1024)
            lds[T_HB + i] = H_g[(size_t)(b * 64 + ch * 8) * n * 32 + i];
        {
            const float* src = (ch < 4)
                ? F_g + (size_t)(b * 32 + ch * 8) * n * 32
                : G_g + (size_t)(b * 32 + (ch - 4) * 8) * n * 32;
            for (int i = tid; i < 8 * n * 32; i += 1024) lds[T_FB + i] = src[i];
        }
        if (tid < n) lds[T_BMX + tid] = bmax0_g[b * 32 + tid];
        __syncthreads();

        for (int w = 1; w < n; ++w) {
            const int S = n - w;
            float* pbW = pbase + (size_t)(w & 3) * SLOTF;

            if (w >= 2) {
                spin12(myflags, (unsigned)(w - 1), tid);
                const int wp = w - 1;
                const bool hasNN = (wp >= 3);
                const float* pbP = pbase + (size_t)(wp & 3) * SLOTF;
                if (tid < (S + 1) * 32) {
                    int s = tid >> 5, aa = tid & 31;
                    float Mp = maxMp(lds + T_BMX, wp, s);
                    float t = finalize_sum(pbP + (size_t)tid * 12, hasNN,
                                           Mp, lds[T_MSP + s]);
                    float m2 = t;
                    for (int off = 16; off > 0; off >>= 1)
                        m2 = fmaxf(m2, __shfl_xor(m2, off, 32));
                    lds[T_BW1 + aa * 30 + s] = t / m2;
                    if (aa == 0)
                        lds[T_BMX + wp * NMAX + s] = __logf(m2) + lds[T_MSP + s];
                }
                __syncthreads();
            }

            // B: M, g0, gw
            if (tid < S) {
                int s = tid;
                float M = maxM(lds + T_BMX, w, s);
                lds[T_MSP + s] = M;
                lds[T_GG + s] =
                    __expf(lds[T_BMX + s] + lds[T_BMX + (w - 1) * NMAX + s + 1] - M);
                lds[T_GG + 32 + s] =
                    __expf(lds[T_BMX + (w - 1) * NMAX + s] + lds[T_BMX + s + w] - M);
            }
            __syncthreads();

            // G: 8-FMA contraction + direct partial store
            if (tid < S * 32) {
                int s = tid >> 5;
                float acc = 0.f;
                if (w == 1) {
                    #pragma unroll
                    for (int j = 0; j < 8; ++j)
                        acc = fmaf(lds[T_ELT + (ch * 8 + j) * 29 + (s + 1)],
                                   lds[T_HB + (j * n + s) * 32 + a], acc);
                } else if (ch < 4) {
                    #pragma unroll
                    for (int j = 0; j < 8; ++j)
                        acc = fmaf(lds[T_BW1 + (ch * 8 + j) * 30 + (s + 1)],
                                   lds[T_FB + (j * n + s) * 32 + a], acc);
                    acc *= lds[T_GG + s];
                } else {
                    #pragma unroll
                    for (int j = 0; j < 8; ++j)
                        acc = fmaf(lds[T_BW1 + ((ch - 4) * 8 + j) * 30 + s],
                                   lds[T_FB + (j * n + (s + w)) * 32 + a], acc);
                    acc *= lds[T_GG + 32 + s];
                }
                gstore(&pbW[(size_t)tid * 12 + ch], acc);
            }
            __syncthreads();   // drains vmcnt -> stores visible
            if (tid == 0) gstoreu(&myflags[ch], (unsigned)w);
        }

        // epilogue (ch==0): width n-1 span 0 + root logsumexp
        if (ch == 0) {
            spin12(myflags, (unsigned)(n - 1), tid);
            if (tid < 32) {
                const int wp = n - 1;
                const float* pbP = pbase + (size_t)(wp & 3) * SLOTF;
                float Mp = maxMp(lds + T_BMX, wp, 0);
                float t = finalize_sum(pbP + (size_t)tid * 12, true,
                                       Mp, lds[T_MSP + 0]);
                float v = __logf(t) + lds[T_MSP + 0] + root[b * 32 + tid];
                float m = v;
                for (int off = 16; off > 0; off >>= 1)
                    m = fmaxf(m, __shfl_xor(m, off, 32));
                float e = __expf(v - m);
                for (int off = 16; off > 0; off >>= 1) e += __shfl_xor(e, off, 32);
                if (tid == 0) out[b] = m + __logf(e);
            }
        }
    } else {
        // ================= NN role (2 rounds ahead) =================
        float4 e4[2];
        {
            const float4* Eq = (const float4*)E_NN + (size_t)b * 8192;
            int base = (ch - 8) * 64 + (tid >> 5) * 2;
            e4[0] = Eq[(size_t)base * 32 + a];
            e4[1] = Eq[(size_t)(base + 1) * 32 + a];
        }
        if (tid < n) lds[N_BMX + tid] = bmax0_g[b * 32 + tid];
        __syncthreads();

        for (int w = 3; w < n; ++w) {
            const int S = n - w, Sp2 = S | 1;
            int q4 = (w - 2 + 3) >> 2; if (!(q4 & 1)) ++q4;
            const int K4 = 4 * q4;
            float* pbW = pbase + (size_t)(w & 3) * SLOTF;

            spin12(myflags, (unsigned)(w - 2), tid);

            // A1: finalize width w-2 into TRI + bmax row
            {
                const int wf = w - 2;
                const bool hasNN = (wf >= 3);
                const float* pbF_ = pbase + (size_t)(wf & 3) * SLOTF;
                if (tid < (n - wf) * 32) {
                    int s = tid >> 5, aa = tid & 31;
                    float Mw = maxM(lds + N_BMX, wf, s);
                    float Mp = maxMp(lds + N_BMX, wf, s);
                    float t = finalize_sum(pbF_ + (size_t)tid * 12, hasNN, Mp, Mw);
                    float m2 = t;
                    for (int off = 16; off > 0; off >>= 1)
                        m2 = fmaxf(m2, __shfl_xor(m2, off, 32));
                    lds[N_TRI + (off32(wf, n) + s) * 32 + aa] = t / m2;
                    if (aa == 0) lds[N_BMX + wf * NMAX + s] = __logf(m2) + Mw;
                }
                __syncthreads();
            }

            // A2: g'[k][s] (normalized by local M')
            if (tid < (w - 2) * 32) {
                int k = (tid >> 5) + 1, s = tid & 31;
                if (s < S) {
                    float Mp = maxMp(lds + N_BMX, w, s);
                    lds[N_GP + k * NMAX + s] =
                        __expf(lds[N_BMX + k * NMAX + s] +
                               lds[N_BMX + (w - 1 - k) * NMAX + s + k + 1] - Mp);
                }
            }
            __syncthreads();

            // A3: k-packed ELK/ERK from TRI (g' folded into ERK)
            if (tid < S * 32) {
                int s = tid >> 5, sym = tid & 31;
                int off = (sym * Sp2 + s) * K4;
                for (int kk = 1; kk <= w - 2; ++kk) {
                    lds[N_ELK + off + kk - 1] =
                        lds[N_TRI + (off32(kk, n) + s) * 32 + sym];
                    lds[N_ERK + off + kk - 1] =
                        lds[N_TRI + (off32(w - 1 - kk, n) + s + kk + 1) * 32 + sym] *
                        lds[N_GP + kk * NMAX + s];
                }
                for (int k = w - 2; k < K4; ++k) {
                    lds[N_ELK + off + k] = 0.f;
                    lds[N_ERK + off + k] = 0.f;
                }
            }
            __syncthreads();

            // C: numer (256 cols, K4 dot) -> bf16 LDS
            {
                const int cL = tid & 255, sh = tid >> 8;
                const int cc = (ch - 8) * 256 + cL;
                const int l = cc >> 5, r = cc & 31;
                unsigned short* np = (unsigned short*)(lds + N_NUM);
                for (int s = sh; s < S; s += 4) {
                    const float* elp = lds + N_ELK + (l * Sp2 + s) * K4;
                    const float* erp = lds + N_ERK + (r * Sp2 + s) * K4;
                    float acc = 0.f;
                    for (int j = 0; j < K4; j += 4)
                        acc = dot4acc(*(const float4*)(elp + j),
                                      *(const float4*)(erp + j), acc);
                    unsigned u = __float_as_uint(acc);
                    np[s * 264 + cL] =
                        (unsigned short)((u + 0x7fffu + ((u >> 16) & 1u)) >> 16);
                }
            }
            __syncthreads();

            // D: contraction (bf16 numer, E regs)
            {
                const char* nb = (const char*)(lds + N_NUM);
                const int g = tid >> 5, wv = tid >> 6;
                const bool low = (tid & 32) == 0;
                for (int s = 0; s < S; ++s) {
                    uint4 u = *(const uint4*)(nb + s * 528 + g * 16);
                    float acc = 0.f;
                    #define LO(q) __uint_as_float((q) << 16)
                    #define HI(q) __uint_as_float((q) & 0xffff0000u)
                    acc = fmaf(LO(u.x), e4[0].x, acc); acc = fmaf(HI(u.x), e4[0].y, acc);
                    acc = fmaf(LO(u.y), e4[0].z, acc); acc = fmaf(HI(u.y), e4[0].w, acc);
                    acc = fmaf(LO(u.z), e4[1].x, acc); acc = fmaf(HI(u.z), e4[1].y, acc);
                    acc = fmaf(LO(u.w), e4[1].z, acc); acc = fmaf(HI(u.w), e4[1].w, acc);
                    #undef LO
                    #undef HI
                    acc += __shfl_xor(acc, 32, 64);
                    if (low) lds[N_RED + wv * 896 + s * 32 + a] = acc;
                }
            }
            __syncthreads();

            // E: 16-group reduce -> partial store
            if (tid < S * 32) {
                float t = 0.f;
                #pragma unroll
                for (int g2 = 0; g2 < 16; ++g2) t += lds[N_RED + g2 * 896 + tid];
                gstore(&pbW[(size_t)tid * 12 + ch], t);
            }
            __syncthreads();   // drains vmcnt
            if (tid == 0) gstoreu(&myflags[ch], (unsigned)w);
        }
    }
}

extern "C" void kernel_launch(void* const* d_in, const int* in_sizes, int n_in,
                              void* d_out, int out_size, void* d_ws, size_t ws_size,
                              hipStream_t stream) {
    const float* unary = (const float*)d_in[0]; // B,n,64
    const float* rule  = (const float*)d_in[1]; // B,32,96,96
    const float* root  = (const float*)d_in[2]; // B,32
    float* out = (float*)d_out;

    const int B = in_sizes[2] / 32;
    int n = in_sizes[0] / (B * 64);

    float* ws = (float*)d_ws;
    float* elT_g = ws;                                   // B*64*n
    float* bmax0 = elT_g + (size_t)B * 64 * n;           // B*32
    float* H_g   = bmax0 + (size_t)B * 32;               // B*64*n*32
    float* F_g   = H_g + (size_t)B * 64 * n * 32;        // B*32*n*32
    float* G_g   = F_g + (size_t)B * 32 * n * 32;        // B*32*n*32
    float* E_NN  = G_g + (size_t)B * 32 * n * 32;        // B*32768
    float* part  = E_NN + (size_t)B * 32768;             // B*4*SLOTF
    unsigned* flags = (unsigned*)(part + (size_t)B * 4 * SLOTF); // B*32

    prep_kernel<<<dim3(B), 256, 0, stream>>>(unary, elT_g, bmax0, flags, n);

    const int packLds = (9216 + 64 * n) * 4;
    hipFuncSetAttribute((const void*)pack_kernel,
                        hipFuncAttributeMaxDynamicSharedMemorySize, packLds);
    pack_kernel<<<dim3(32, B), 256, packLds, stream>>>(rule, elT_g, H_g, F_g,
                                                       G_g, E_NN, n);

    hipFuncSetAttribute((const void*)inside_kernel,
                        hipFuncAttributeMaxDynamicSharedMemorySize, LDSF * 4);
    void* args[] = {
        (void*)&elT_g, (void*)&bmax0, (void*)&H_g, (void*)&F_g, (void*)&G_g,
        (void*)&E_NN, (void*)&part, (void*)&root, (void*)&out,
        (void*)&flags, (void*)&n
    };
    hipLaunchCooperativeKernel((void*)inside_kernel, dim3(B * 12), dim3(1024),
                               args, LDSF * 4, stream);
}

// Round 15
// 260.839 us; speedup vs baseline: 1.2099x; 1.2079x over previous
//
#include <hip/hip_runtime.h>
#include <cstdint>
#include <cstddef>

// PCFG inside algorithm. B=8, n=28, NT=32, T=64, ST=96.
// v7: a-sliced local row chain + edge peeling + parity-split NN core.
// Grid B*16 blocks, 1024 thr.
//  ch0-7  row blocks: own 4 symbols. Per width w: finalize row w-1 (1 load/elem
//    from t2 ring), then t2 slice = TT(H)|TN(F)+NT(G)+edge1(F2)+edgew(G2)+core
//    (4 ring loads) -- ALL local tables; publish t2 slice + flag_row.
//  ch8-15 core blocks: 2 parity groups x 4 c-slices (128 pair-cols each, E in
//    regs). Group p handles widths W (W&1==p), W=5..n-1: finalize rows up to
//    W-3 locally, build k-packed ELK/ERK (k in 2..W-3, norm by local Mc),
//    bf16 numer, contract, publish 4-way c-partials + flag_nn.
// Tables (pack): F[r][s][a]=sum_l elT*exp(rule[a][32+l][r]); G, H analogous;
// F2/G2 = eB1-folded E_NN built in-kernel at w==2. exp(mrule) folded away.
// Rings: t2 depth 8, core depth 4; flag targets make reuse WAR-safe.
// All cross-block data via agent-scope (uncached) atomics; flags reset in prep.

#define NMAX 28
#define SLOTT 864
#define SLOTN 3456

// row-role LDS offsets (floats)
#define R_ELT 0      // 1856 = 64*29
#define R_F   1856   // 3712 = 32*29*4
#define R_G   5568   // 3712
#define R_F2  9280   // 3712  (H[64*29*4]=7424 aliases F2+G2 during w==1)
#define R_G2  12992  // 3712
#define R_TRI 16704  // bf16 377*32 = 6032 f
#define R_BMX 22736  // 784
#define R_ENA 23520  // 4096
// core-role LDS offsets
#define C_TRI 0      // 6032
#define C_BMX 6032   // 784
#define C_GPP 6816   // 768
#define C_ELK 7584   // 1024
#define C_ERK 8608   // 6144
#define C_NUM 14752  // 1784 (ushort pitch 132)
#define C_RED 16536  // 7168 (bf16 16*896)
#define LDSF  27616

__device__ __forceinline__ int off32(int w, int n) {
    return (w - 1) * n - (w * (w - 1)) / 2;
}
__device__ __forceinline__ float gload(const float* p) {
    return __hip_atomic_load(p, __ATOMIC_RELAXED, __HIP_MEMORY_SCOPE_AGENT);
}
__device__ __forceinline__ void gstore(float* p, float v) {
    __hip_atomic_store(p, v, __ATOMIC_RELAXED, __HIP_MEMORY_SCOPE_AGENT);
}
__device__ __forceinline__ unsigned gloadu(const unsigned* p) {
    return __hip_atomic_load(p, __ATOMIC_RELAXED, __HIP_MEMORY_SCOPE_AGENT);
}
__device__ __forceinline__ void gstoreu(unsigned* p, unsigned v) {
    __hip_atomic_store(p, v, __ATOMIC_RELAXED, __HIP_MEMORY_SCOPE_AGENT);
}
__device__ __forceinline__ float dot4acc(float4 m, float4 t, float acc) {
    return fmaf(m.x, t.x, fmaf(m.y, t.y, fmaf(m.z, t.z, fmaf(m.w, t.w, acc))));
}
__device__ __forceinline__ float b2f(unsigned short u) {
    return __uint_as_float(((unsigned)u) << 16);
}
__device__ __forceinline__ unsigned short f2b(float x) {
    unsigned u = __float_as_uint(x);
    return (unsigned short)((u + 0x7fffu + ((u >> 16) & 1u)) >> 16);
}
__device__ __forceinline__ float maxM(const float* bmx, int w, int s) {
    float M = -3.0e38f;
    for (int k = 0; k < w; ++k)
        M = fmaxf(M, bmx[k * NMAX + s] + bmx[(w - 1 - k) * NMAX + s + k + 1]);
    return M;
}
__device__ __forceinline__ float maxMc(const float* bmx, int w, int s) {
    float M = -3.0e38f;
    for (int k = 2; k <= w - 3; ++k)
        M = fmaxf(M, bmx[k * NMAX + s] + bmx[(w - 1 - k) * NMAX + s + k + 1]);
    return M;
}
// shared finalize: identical codegen across roles (bitwise-consistent rows)
__device__ __forceinline__ void finalize_row(float* lds, int triOff, int bmxOff,
                                             const float* slot, int wf, int n,
                                             int tid) {
    int Sp = n - wf;
    if (tid < Sp * 32) {
        int s = tid >> 5, aa = tid & 31;
        float q = gload(slot + s * 32 + aa);
        float m2 = q;
        for (int off = 16; off > 0; off >>= 1)
            m2 = fmaxf(m2, __shfl_xor(m2, off, 32));
        ((unsigned short*)(lds + triOff))[(off32(wf, n) + s) * 32 + aa] = f2b(q / m2);
        if (aa == 0)
            lds[bmxOff + wf * NMAX + s] = __logf(m2) + maxM(lds + bmxOff, wf, s);
    }
}

// ---- prep: elT, bmax0, flag init ----
__global__ __launch_bounds__(256) void prep_kernel(const float* __restrict__ unary,
                                                   float* __restrict__ elT_g,
                                                   float* __restrict__ bmax0_g,
                                                   unsigned* __restrict__ flags,
                                                   int n) {
    int b = blockIdx.x, tid = threadIdx.x;
    if (tid < 16) gstoreu(&flags[b * 32 + tid], (tid >= 8) ? 4u : 0u);
    for (int pos = tid >> 6; pos < n; pos += 4) {
        int t = tid & 63;
        float v = unary[((size_t)(b * n) + pos) * 64 + t];
        float m = v;
        for (int off = 32; off > 0; off >>= 1) m = fmaxf(m, __shfl_xor(m, off, 64));
        elT_g[(size_t)b * 64 * n + t * n + pos] = __expf(v - m);
        if (t == 0) bmax0_g[b * 32 + pos] = m;
    }
}

// ---- pack: per (b,a) block: exp slice -> H, F, G, E_NN (2 formats) ----
__global__ __launch_bounds__(256) void pack_kernel(const float* __restrict__ rule,
                                                   const float* __restrict__ elT_g,
                                                   float* __restrict__ H_g,
                                                   float* __restrict__ F_g,
                                                   float* __restrict__ G_g,
                                                   float* __restrict__ ENa_g,
                                                   float* __restrict__ ENc_g,
                                                   int n) {
    extern __shared__ float sl[];   // 9216 exp slice + 64*n elT
    int b = blockIdx.y, aa = blockIdx.x, tid = threadIdx.x;
    const int ag = aa >> 2, a4 = aa & 3;
    const float4* rs4 = (const float4*)(rule + (size_t)(b * 32 + aa) * 9216);
    for (int i = tid; i < 2304; i += 256) {
        float4 v = rs4[i];
        float4 o;
        o.x = __expf(v.x); o.y = __expf(v.y); o.z = __expf(v.z); o.w = __expf(v.w);
        ((float4*)sl)[i] = o;
    }
    for (int i = tid; i < 64 * n; i += 256)
        sl[9216 + i] = elT_g[(size_t)b * 64 * n + i];
    __syncthreads();
    const float* elt = sl + 9216;
    // E_NN c-packed [c4][a][4] and a-major [a][l*32+r]
    if (tid < 256) {
        int flat = tid * 4, l = flat >> 5, r = flat & 31;
        float4 o = *(const float4*)(sl + l * 96 + r);
        *(float4*)(ENc_g + ((size_t)(b * 256 + tid) * 32 + aa) * 4) = o;
    }
    for (int i = tid; i < 1024; i += 256)
        ENa_g[((size_t)(b * 8 + ag) * 4096) + a4 * 1024 + i] = sl[(i >> 5) * 96 + (i & 31)];
    // H[r64][s][a4]
    for (int i = tid; i < 64 * n; i += 256) {
        int r = i / n, s = i - r * n;
        float acc = 0.f;
        for (int l = 0; l < 64; ++l)
            acc = fmaf(elt[l * n + s], sl[(32 + l) * 96 + 32 + r], acc);
        H_g[(size_t)(b * 8 + ag) * 7424 + (r * 29 + s) * 4 + a4] = acc;
    }
    // F[r32][s][a4]
    for (int i = tid; i < 32 * n; i += 256) {
        int r = i / n, s = i - r * n;
        float acc = 0.f;
        for (int l = 0; l < 64; ++l)
            acc = fmaf(elt[l * n + s], sl[(32 + l) * 96 + r], acc);
        F_g[(size_t)(b * 8 + ag) * 3712 + (r * 29 + s) * 4 + a4] = acc;
    }
    // G[l32][s'][a4]
    for (int i = tid; i < 32 * n; i += 256) {
        int l = i / n, s = i - l * n;
        float acc = 0.f;
        for (int r = 0; r < 64; ++r)
            acc = fmaf(elt[r * n + s], sl[l * 96 + 32 + r], acc);
        G_g[(size_t)(b * 8 + ag) * 3712 + (l * 29 + s) * 4 + a4] = acc;
    }
}

__global__ __launch_bounds__(1024, 1) void inside_kernel(
    const float* __restrict__ elT_g, const float* __restrict__ bmax0_g,
    const float* __restrict__ H_g, const float* __restrict__ F_g,
    const float* __restrict__ G_g, const float* __restrict__ ENa_g,
    const float* __restrict__ ENc_g,
    float* __restrict__ ringT, float* __restrict__ ringN,
    const float* __restrict__ root, float* __restrict__ out,
    unsigned* __restrict__ flags, int n) {
    extern __shared__ float lds[];
    const int b = blockIdx.x >> 4, ch = blockIdx.x & 15;
    const int tid = threadIdx.x;
    unsigned* const fl = flags + b * 32;
    float* const rT = ringT + (size_t)b * 8 * SLOTT;
    float* const rN = ringN + (size_t)b * 4 * SLOTN;

    if (ch < 8) {
        // =============== row role (a-slice ch*4..ch*4+3) ===============
        for (int i = tid; i < 64 * n; i += 1024) {
            int t = i / n, pos = i - t * n;
            lds[R_ELT + t * 29 + pos] = elT_g[(size_t)b * 64 * n + i];
        }
        for (int i = tid; i < 3712; i += 1024) lds[R_F + i] = F_g[(size_t)(b * 8 + ch) * 3712 + i];
        for (int i = tid; i < 3712; i += 1024) lds[R_G + i] = G_g[(size_t)(b * 8 + ch) * 3712 + i];
        for (int i = tid; i < 7424; i += 1024) lds[R_F2 + i] = H_g[(size_t)(b * 8 + ch) * 7424 + i];
        for (int i = tid; i < 4096; i += 1024) lds[R_ENA + i] = ENa_g[(size_t)(b * 8 + ch) * 4096 + i];
        if (tid < n) lds[R_BMX + tid] = bmax0_g[b * 32 + tid];
        __syncthreads();

        for (int w = 1; w < n; ++w) {
            const int S = n - w;
            // spin: row flags >= w-1 ; same-parity core flags >= w (w>=5)
            if (tid < 64) {
                unsigned tgt = 0u;
                if (tid < 8) tgt = (w >= 2) ? (unsigned)(w - 1) : 0u;
                else if (tid < 16 && w >= 5) {
                    int p = (tid - 8) >> 2;
                    if (p == (w & 1)) tgt = (unsigned)w;
                }
                for (;;) {
                    unsigned v = (tid < 16) ? gloadu(&fl[tid]) : 0u;
                    if (__ballot(v < tgt) == 0ull) break;
                    __builtin_amdgcn_s_sleep(1);
                }
            }
            __syncthreads();

            if (w >= 2)
                finalize_row(lds, R_TRI, R_BMX, rT + (size_t)((w - 1) & 7) * SLOTT,
                             w - 1, n, tid);
            __syncthreads();

            if (w == 2) {   // build F2/G2 from row 1 (overwrites H region)
                const unsigned short* tri = (const unsigned short*)(lds + R_TRI);
                const int b1 = off32(1, n);
                for (int i = tid; i < 32 * 29 * 4; i += 1024) {
                    int a4 = i & 3, rest = i >> 2, s = rest % 29, rl = rest / 29;
                    if (s < n - 1) {
                        float accF = 0.f, accG = 0.f;
                        for (int q = 0; q < 32; ++q) {
                            float e1 = b2f(tri[(b1 + s) * 32 + q]);
                            accF = fmaf(e1, lds[R_ENA + a4 * 1024 + q * 32 + rl], accF);
                            accG = fmaf(lds[R_ENA + a4 * 1024 + rl * 32 + q], e1, accG);
                        }
                        lds[R_F2 + (rl * 29 + s) * 4 + a4] = accF;
                        lds[R_G2 + (rl * 29 + s) * 4 + a4] = accG;
                    }
                }
                __syncthreads();
            }

            // t2 slice
            if (tid < S * 4) {
                int s = tid >> 2, a4 = tid & 3, a = ch * 4 + a4;
                float cr0 = 0.f, cr1 = 0.f, cr2 = 0.f, cr3 = 0.f;
                if (w >= 5) {
                    const float* p = rN + (size_t)(w & 3) * SLOTN + (size_t)(s * 32 + a) * 4;
                    cr0 = gload(p); cr1 = gload(p + 1); cr2 = gload(p + 2); cr3 = gload(p + 3);
                }
                float M = maxM(lds + R_BMX, w, s);
                const unsigned short* tri = (const unsigned short*)(lds + R_TRI);
                float t2;
                if (w == 1) {
                    float acc = 0.f;
                    for (int r = 0; r < 64; ++r)
                        acc = fmaf(lds[R_ELT + r * 29 + s + 1],
                                   lds[R_F2 + (r * 29 + s) * 4 + a4], acc);  // H alias
                    t2 = acc;
                } else {
                    int b1 = off32(w - 1, n);
                    float aTN = 0.f, aNT = 0.f;
                    for (int r = 0; r < 32; ++r)
                        aTN = fmaf(b2f(tri[(b1 + s + 1) * 32 + r]),
                                   lds[R_F + (r * 29 + s) * 4 + a4], aTN);
                    for (int l = 0; l < 32; ++l)
                        aNT = fmaf(b2f(tri[(b1 + s) * 32 + l]),
                                   lds[R_G + (l * 29 + s + w) * 4 + a4], aNT);
                    float g0 = __expf(lds[R_BMX + s] + lds[R_BMX + (w - 1) * NMAX + s + 1] - M);
                    float gw = __expf(lds[R_BMX + (w - 1) * NMAX + s] + lds[R_BMX + s + w] - M);
                    t2 = aTN * g0 + aNT * gw;
                    if (w >= 3) {
                        int b2 = off32(w - 2, n);
                        float e1 = 0.f;
                        for (int r = 0; r < 32; ++r)
                            e1 = fmaf(b2f(tri[(b2 + s + 2) * 32 + r]),
                                      lds[R_F2 + (r * 29 + s) * 4 + a4], e1);
                        t2 = fmaf(e1, __expf(lds[R_BMX + NMAX + s] +
                                             lds[R_BMX + (w - 2) * NMAX + s + 2] - M), t2);
                        if (w >= 4) {
                            float e2 = 0.f;
                            for (int l = 0; l < 32; ++l)
                                e2 = fmaf(b2f(tri[(b2 + s) * 32 + l]),
                                          lds[R_G2 + (l * 29 + s + w - 1) * 4 + a4], e2);
                            t2 = fmaf(e2, __expf(lds[R_BMX + (w - 2) * NMAX + s] +
                                                 lds[R_BMX + NMAX + s + w - 1] - M), t2);
                        }
                    }
                    if (w >= 5) {
                        float Mc = maxMc(lds + R_BMX, w, s);
                        t2 = fmaf(((cr0 + cr1) + (cr2 + cr3)), __expf(Mc - M), t2);
                    }
                }
                gstore(rT + (size_t)(w & 7) * SLOTT + s * 32 + a, t2);
            }
            __syncthreads();
            if (tid == 0) gstoreu(&fl[ch], (unsigned)w);
        }

        // epilogue
        if (ch == 0) {
            if (tid < 64) {
                unsigned tgt = (unsigned)(n - 1);
                for (;;) {
                    unsigned v = (tid < 8) ? gloadu(&fl[tid]) : tgt;
                    if (__ballot(v < tgt) == 0ull) break;
                    __builtin_amdgcn_s_sleep(1);
                }
            }
            __syncthreads();
            if (tid < 32) {
                float q = gload(rT + (size_t)((n - 1) & 7) * SLOTT + tid);
                float v = q * __expf(root[b * 32 + tid]);
                for (int off = 16; off > 0; off >>= 1) v += __shfl_xor(v, off, 32);
                if (tid == 0) out[b] = maxM(lds + R_BMX, n - 1, 0) + __logf(v);
            }
        }
    } else {
        // =============== core role (parity group, c-slice) ===============
        const int idx = ch - 8, slice = idx & 3, par = idx >> 2;
        float4 e4;
        {
            int g = tid >> 5, a = tid & 31;
            e4 = *(const float4*)(ENc_g + ((size_t)(b * 256 + slice * 32 + g) * 32 + a) * 4);
        }
        if (tid < n) lds[C_BMX + tid] = bmax0_g[b * 32 + tid];
        __syncthreads();
        int lastFin = 0;
        const int W0 = (par == 1) ? 5 : 6;
        for (int W = W0; W < n; W += 2) {
            const int S = n - W, Sp2 = S | 1;
            const int cnt = W - 4;
            int q4 = (cnt + 3) >> 2; if (!(q4 & 1)) ++q4;
            const int K4 = 4 * q4;
            // spin: row flags >= W-3
            if (tid < 64) {
                unsigned tgt = (unsigned)(W - 3);
                for (;;) {
                    unsigned v = (tid < 8) ? gloadu(&fl[tid]) : tgt;
                    if (__ballot(v < tgt) == 0ull) break;
                    __builtin_amdgcn_s_sleep(1);
                }
            }
            __syncthreads();
            for (int wf = lastFin + 1; wf <= W - 3; ++wf) {
                finalize_row(lds, C_TRI, C_BMX, rT + (size_t)(wf & 7) * SLOTT, wf, n, tid);
                __syncthreads();
            }
            lastFin = W - 3;
            // A2: g'' table (norm by local Mc)
            if (tid < cnt * 32) {
                int k = (tid >> 5) + 2, s = tid & 31;
                if (s < S) {
                    float Mc = maxMc(lds + C_BMX, W, s);
                    lds[C_GPP + (k - 2) * 32 + s] =
                        __expf(lds[C_BMX + k * NMAX + s] +
                               lds[C_BMX + (W - 1 - k) * NMAX + s + k + 1] - Mc);
                }
            }
            __syncthreads();
            // A3: k-packed ELK/ERK
            if (tid < S * 32) {
                int s = tid >> 5, sym = tid & 31;
                const unsigned short* tri = (const unsigned short*)(lds + C_TRI);
                int eo = (sym * Sp2 + s) * K4;
                for (int k = 2; k <= W - 3; ++k)
                    lds[C_ERK + eo + k - 2] =
                        b2f(tri[(off32(W - 1 - k, n) + s + k + 1) * 32 + sym]) *
                        lds[C_GPP + (k - 2) * 32 + s];
                for (int j = cnt; j < K4; ++j) lds[C_ERK + eo + j] = 0.f;
                if (sym < 4) {
                    int lo = (sym * Sp2 + s) * K4;
                    int gl = slice * 4 + sym;
                    for (int k = 2; k <= W - 3; ++k)
                        lds[C_ELK + lo + k - 2] = b2f(tri[(off32(k, n) + s) * 32 + gl]);
                    for (int j = cnt; j < K4; ++j) lds[C_ELK + lo + j] = 0.f;
                }
            }
            __syncthreads();
            // C: numer (128 cols) -> bf16
            {
                int cL = tid & 127, sh = tid >> 7;
                int lloc = cL >> 5, r = cL & 31;
                unsigned short* np = (unsigned short*)(lds + C_NUM);
                for (int s = sh; s < S; s += 8) {
                    const float* ep = lds + C_ELK + (lloc * Sp2 + s) * K4;
                    const float* rp = lds + C_ERK + (r * Sp2 + s) * K4;
                    float acc = 0.f;
                    for (int j = 0; j < K4; j += 4)
                        acc = dot4acc(*(const float4*)(ep + j), *(const float4*)(rp + j), acc);
                    np[s * 132 + cL] = f2b(acc);
                }
            }
            __syncthreads();
            // D: contract vs E regs, wave-pair reduce
            {
                const unsigned short* np = (const unsigned short*)(lds + C_NUM);
                unsigned short* red = (unsigned short*)(lds + C_RED);
                int g = tid >> 5, a = tid & 31, wv = tid >> 6;
                bool low = (tid & 32) == 0;
                for (int s = 0; s < S; ++s) {
                    const unsigned short* pp = np + s * 132 + g * 4;
                    float acc = b2f(pp[0]) * e4.x + b2f(pp[1]) * e4.y +
                                b2f(pp[2]) * e4.z + b2f(pp[3]) * e4.w;
                    acc += __shfl_xor(acc, 32, 64);
                    if (low) red[wv * 896 + s * 32 + a] = f2b(acc);
                }
            }
            __syncthreads();
            // E: publish c-partials
            if (tid < S * 32) {
                const unsigned short* red = (const unsigned short*)(lds + C_RED);
                float t = 0.f;
                for (int g2 = 0; g2 < 16; ++g2) t += b2f(red[g2 * 896 + tid]);
                gstore(rN + (size_t)(W & 3) * SLOTN + (size_t)tid * 4 + slice, t);
            }
            __syncthreads();
            if (tid == 0) gstoreu(&fl[ch], (unsigned)W);
        }
    }
}

extern "C" void kernel_launch(void* const* d_in, const int* in_sizes, int n_in,
                              void* d_out, int out_size, void* d_ws, size_t ws_size,
                              hipStream_t stream) {
    const float* unary = (const float*)d_in[0]; // B,n,64
    const float* rule  = (const float*)d_in[1]; // B,32,96,96
    const float* root  = (const float*)d_in[2]; // B,32
    float* out = (float*)d_out;

    const int B = in_sizes[2] / 32;
    int n = in_sizes[0] / (B * 64);

    float* ws = (float*)d_ws;
    float* elT_g = ws;                                  // B*64*n
    float* bmax0 = elT_g + (size_t)B * 64 * n;          // B*32
    float* H_g   = bmax0 + (size_t)B * 32;              // B*8*7424
    float* F_g   = H_g + (size_t)B * 8 * 7424;          // B*8*3712
    float* G_g   = F_g + (size_t)B * 8 * 3712;          // B*8*3712
    float* ENa_g = G_g + (size_t)B * 8 * 3712;          // B*8*4096
    float* ENc_g = ENa_g + (size_t)B * 8 * 4096;        // B*32768
    float* ringT = ENc_g + (size_t)B * 32768;           // B*8*SLOTT
    float* ringN = ringT + (size_t)B * 8 * SLOTT;       // B*4*SLOTN
    unsigned* flags = (unsigned*)(ringN + (size_t)B * 4 * SLOTN); // B*32

    prep_kernel<<<dim3(B), 256, 0, stream>>>(unary, elT_g, bmax0, flags, n);

    const int packLds = (9216 + 64 * n) * 4;
    hipFuncSetAttribute((const void*)pack_kernel,
                        hipFuncAttributeMaxDynamicSharedMemorySize, packLds);
    pack_kernel<<<dim3(32, B), 256, packLds, stream>>>(rule, elT_g, H_g, F_g,
                                                       G_g, ENa_g, ENc_g, n);

    hipFuncSetAttribute((const void*)inside_kernel,
                        hipFuncAttributeMaxDynamicSharedMemorySize, LDSF * 4);
    void* args[] = {
        (void*)&elT_g, (void*)&bmax0, (void*)&H_g, (void*)&F_g, (void*)&G_g,
        (void*)&ENa_g, (void*)&ENc_g, (void*)&ringT, (void*)&ringN,
        (void*)&root, (void*)&out, (void*)&flags, (void*)&n
    };
    hipLaunchCooperativeKernel((void*)inside_kernel, dim3(B * 16), dim3(1024),
                               args, LDSF * 4, stream);
}

// Round 16
// 233.718 us; speedup vs baseline: 1.3503x; 1.1160x over previous
//
#include <hip/hip_runtime.h>
#include <cstdint>
#include <cstddef>

// PCFG inside algorithm. B=8, n=28, NT=32, T=64, ST=96.
// v8 = v7 fixed: a-sliced row chain + edge peeling + parity-split NN core.
// Grid B*16 blocks, 1024 thr.
//  ch0-7  row blocks (a-slice of 4 symbols): per width, prefetch ring loads,
//    finalize row w-1 (f32 TRI), t2 slice via width-invariant tables
//    (H/F/G + F2/G2 from row 1) + core ring term; 8 sub-lanes per (s,a4).
//  ch8-15 core blocks: 2 parity groups x 4 slices (256 pair-cols each = ALL
//    1024 NN pairs, fixing R15's missing-l bug). Core(W) needs rows <= W-3
//    (k in 2..W-3, local Mc norm) -> 3-period window. ERK sized 7296 (fixes
//    R15 overflow). bf16 numer + bf16 RED; everything else f32.
// Sync: monotone per-block flags + spin; rings rT depth 8, rN depth 4.
// All cross-block data via agent-scope (uncached) atomics; flags reset in prep.

#define NMAX 28
#define SLOTT 864
#define SLOTN 3456

// row-role LDS offsets (floats)
#define R_ELT 0      // 1856
#define R_F   1856   // 3712
#define R_G   5568   // 3712
#define R_F2  9280   // 3712 (H 7424 aliases F2+G2 during w==1)
#define R_G2  12992  // 3712
#define R_TRI 16704  // f32 377*32 = 12064
#define R_BMX 28768  // 784
#define R_ENA 29552  // 4096 -> 33648
// core-role LDS offsets
#define C_TRI 0      // 12064 (f32)
#define C_BMX 12064  // 784
#define C_ELK 12848  // 2048
#define C_ERK 14896  // 7296
#define C_NUM 22192  // 3512 (ushort pitch 260)
#define C_RED 25704  // 7168 (bf16 16*896)
#define LDSF  33648  // max(row 33648, core 32872)

__device__ __forceinline__ int off32(int w, int n) {
    return (w - 1) * n - (w * (w - 1)) / 2;
}
__device__ __forceinline__ float gload(const float* p) {
    return __hip_atomic_load(p, __ATOMIC_RELAXED, __HIP_MEMORY_SCOPE_AGENT);
}
__device__ __forceinline__ void gstore(float* p, float v) {
    __hip_atomic_store(p, v, __ATOMIC_RELAXED, __HIP_MEMORY_SCOPE_AGENT);
}
__device__ __forceinline__ unsigned gloadu(const unsigned* p) {
    return __hip_atomic_load(p, __ATOMIC_RELAXED, __HIP_MEMORY_SCOPE_AGENT);
}
__device__ __forceinline__ void gstoreu(unsigned* p, unsigned v) {
    __hip_atomic_store(p, v, __ATOMIC_RELAXED, __HIP_MEMORY_SCOPE_AGENT);
}
__device__ __forceinline__ float dot4acc(float4 m, float4 t, float acc) {
    return fmaf(m.x, t.x, fmaf(m.y, t.y, fmaf(m.z, t.z, fmaf(m.w, t.w, acc))));
}
__device__ __forceinline__ float b2f(unsigned short u) {
    return __uint_as_float(((unsigned)u) << 16);
}
__device__ __forceinline__ unsigned short f2b(float x) {
    unsigned u = __float_as_uint(x);
    return (unsigned short)((u + 0x7fffu + ((u >> 16) & 1u)) >> 16);
}
__device__ __forceinline__ float maxM(const float* bmx, int w, int s) {
    float M = -3.0e38f;
    for (int k = 0; k < w; ++k)
        M = fmaxf(M, bmx[k * NMAX + s] + bmx[(w - 1 - k) * NMAX + s + k + 1]);
    return M;
}
__device__ __forceinline__ float maxMc(const float* bmx, int w, int s) {
    float M = -3.0e38f;
    for (int k = 2; k <= w - 3; ++k)
        M = fmaxf(M, bmx[k * NMAX + s] + bmx[(w - 1 - k) * NMAX + s + k + 1]);
    return M;
}

// ---- prep: elT, bmax0, flag init ----
__global__ __launch_bounds__(256) void prep_kernel(const float* __restrict__ unary,
                                                   float* __restrict__ elT_g,
                                                   float* __restrict__ bmax0_g,
                                                   unsigned* __restrict__ flags,
                                                   int n) {
    int b = blockIdx.x, tid = threadIdx.x;
    if (tid < 16) gstoreu(&flags[b * 32 + tid], (tid >= 8) ? 4u : 0u);
    for (int pos = tid >> 6; pos < n; pos += 4) {
        int t = tid & 63;
        float v = unary[((size_t)(b * n) + pos) * 64 + t];
        float m = v;
        for (int off = 32; off > 0; off >>= 1) m = fmaxf(m, __shfl_xor(m, off, 64));
        elT_g[(size_t)b * 64 * n + t * n + pos] = __expf(v - m);
        if (t == 0) bmax0_g[b * 32 + pos] = m;
    }
}

// ---- pack: per (b,a) block: exp(rule) slice -> H, F, G, ENa, ENc ----
__global__ __launch_bounds__(256) void pack_kernel(const float* __restrict__ rule,
                                                   const float* __restrict__ elT_g,
                                                   float* __restrict__ H_g,
                                                   float* __restrict__ F_g,
                                                   float* __restrict__ G_g,
                                                   float* __restrict__ ENa_g,
                                                   float* __restrict__ ENc_g,
                                                   int n) {
    extern __shared__ float sl[];   // 9216 exp slice + 64*n elT
    int b = blockIdx.y, aa = blockIdx.x, tid = threadIdx.x;
    const int ag = aa >> 2, a4 = aa & 3;
    const float4* rs4 = (const float4*)(rule + (size_t)(b * 32 + aa) * 9216);
    for (int i = tid; i < 2304; i += 256) {
        float4 v = rs4[i];
        float4 o;
        o.x = __expf(v.x); o.y = __expf(v.y); o.z = __expf(v.z); o.w = __expf(v.w);
        ((float4*)sl)[i] = o;
    }
    for (int i = tid; i < 64 * n; i += 256)
        sl[9216 + i] = elT_g[(size_t)b * 64 * n + i];
    __syncthreads();
    const float* elt = sl + 9216;
    // E_NN c-packed [c4][a][4] and a-major [a][l*32+r]
    if (tid < 256) {
        int flat = tid * 4, l = flat >> 5, r = flat & 31;
        float4 o = *(const float4*)(sl + l * 96 + r);
        *(float4*)(ENc_g + ((size_t)(b * 256 + tid) * 32 + aa) * 4) = o;
    }
    for (int i = tid; i < 1024; i += 256)
        ENa_g[((size_t)(b * 8 + ag) * 4096) + a4 * 1024 + i] = sl[(i >> 5) * 96 + (i & 31)];
    // H[r64][s][a4]
    for (int i = tid; i < 64 * n; i += 256) {
        int r = i / n, s = i - r * n;
        float acc = 0.f;
        for (int l = 0; l < 64; ++l)
            acc = fmaf(elt[l * n + s], sl[(32 + l) * 96 + 32 + r], acc);
        H_g[(size_t)(b * 8 + ag) * 7424 + (r * 29 + s) * 4 + a4] = acc;
    }
    // F[r32][s][a4]
    for (int i = tid; i < 32 * n; i += 256) {
        int r = i / n, s = i - r * n;
        float acc = 0.f;
        for (int l = 0; l < 64; ++l)
            acc = fmaf(elt[l * n + s], sl[(32 + l) * 96 + r], acc);
        F_g[(size_t)(b * 8 + ag) * 3712 + (r * 29 + s) * 4 + a4] = acc;
    }
    // G[l32][s'][a4]
    for (int i = tid; i < 32 * n; i += 256) {
        int l = i / n, s = i - l * n;
        float acc = 0.f;
        for (int r = 0; r < 64; ++r)
            acc = fmaf(elt[r * n + s], sl[l * 96 + 32 + r], acc);
        G_g[(size_t)(b * 8 + ag) * 3712 + (l * 29 + s) * 4 + a4] = acc;
    }
}

__global__ __launch_bounds__(1024, 1) void inside_kernel(
    const float* __restrict__ elT_g, const float* __restrict__ bmax0_g,
    const float* __restrict__ H_g, const float* __restrict__ F_g,
    const float* __restrict__ G_g, const float* __restrict__ ENa_g,
    const float* __restrict__ ENc_g,
    float* __restrict__ ringT, float* __restrict__ ringN,
    const float* __restrict__ root, float* __restrict__ out,
    unsigned* __restrict__ flags, int n) {
    extern __shared__ float lds[];
    const int b = blockIdx.x >> 4, ch = blockIdx.x & 15;
    const int tid = threadIdx.x;
    unsigned* const fl = flags + b * 32;
    float* const rT = ringT + (size_t)b * 8 * SLOTT;
    float* const rN = ringN + (size_t)b * 4 * SLOTN;

    if (ch < 8) {
        // =============== row role (symbols ch*4..ch*4+3) ===============
        for (int i = tid; i < 64 * n; i += 1024) {
            int t = i / n, pos = i - t * n;
            lds[R_ELT + t * 29 + pos] = elT_g[(size_t)b * 64 * n + i];
        }
        for (int i = tid; i < 3712; i += 1024) lds[R_F + i] = F_g[(size_t)(b * 8 + ch) * 3712 + i];
        for (int i = tid; i < 3712; i += 1024) lds[R_G + i] = G_g[(size_t)(b * 8 + ch) * 3712 + i];
        for (int i = tid; i < 7424; i += 1024) lds[R_F2 + i] = H_g[(size_t)(b * 8 + ch) * 7424 + i];
        for (int i = tid; i < 4096; i += 1024) lds[R_ENA + i] = ENa_g[(size_t)(b * 8 + ch) * 4096 + i];
        if (tid < n) lds[R_BMX + tid] = bmax0_g[b * 32 + tid];
        __syncthreads();

        for (int w = 1; w < n; ++w) {
            const int S = n - w;
            const int q = tid >> 3, lane8 = tid & 7;

            // spin: row flags >= w-1 ; same-parity core flag >= w (w>=5)
            if (tid < 64) {
                unsigned tgt = 0u;
                if (tid < 8) tgt = (w >= 2) ? (unsigned)(w - 1) : 0u;
                else if (tid < 16 && w >= 5) {
                    int p = (tid - 8) >> 2;
                    if (p == (w & 1)) tgt = (unsigned)w;
                }
                for (;;) {
                    unsigned v = (tid < 16) ? gloadu(&fl[tid]) : 0u;
                    if (__ballot(v < tgt) == 0ull) break;
                    __builtin_amdgcn_s_sleep(1);
                }
            }
            __syncthreads();

            // prefetch both uncached rounds together (latencies overlap)
            float crPre = 0.f, qf = 0.f;
            if (w >= 5 && lane8 < 4 && q < S * 4) {
                int s0 = q >> 2, aa = ch * 4 + (q & 3);
                crPre = gload(rN + (size_t)(w & 3) * SLOTN +
                              (size_t)(s0 * 32 + aa) * 4 + lane8);
            }
            if (w >= 2 && tid < (S + 1) * 32)
                qf = gload(rT + (size_t)((w - 1) & 7) * SLOTT + tid);

            // finalize row w-1 (f32 TRI)
            if (w >= 2 && tid < (S + 1) * 32) {
                int s = tid >> 5, aa = tid & 31;
                float m2 = qf;
                for (int off = 16; off > 0; off >>= 1)
                    m2 = fmaxf(m2, __shfl_xor(m2, off, 32));
                lds[R_TRI + (off32(w - 1, n) + s) * 32 + aa] = qf / m2;
                if (aa == 0)
                    lds[R_BMX + (w - 1) * NMAX + s] =
                        __logf(m2) + maxM(lds + R_BMX, w - 1, s);
            }
            __syncthreads();

            if (w == 2) {   // build F2/G2 from row 1 (overwrites H region)
                const int b1 = off32(1, n);
                for (int i = tid; i < 32 * 29 * 4; i += 1024) {
                    int a4 = i & 3, rest = i >> 2, s = rest % 29, rl = rest / 29;
                    if (s < n - 1) {
                        float accF = 0.f, accG = 0.f;
                        for (int qq = 0; qq < 32; ++qq) {
                            float e1 = lds[R_TRI + (b1 + s) * 32 + qq];
                            accF = fmaf(e1, lds[R_ENA + a4 * 1024 + qq * 32 + rl], accF);
                            accG = fmaf(lds[R_ENA + a4 * 1024 + rl * 32 + qq], e1, accG);
                        }
                        lds[R_F2 + (rl * 29 + s) * 4 + a4] = accF;
                        lds[R_G2 + (rl * 29 + s) * 4 + a4] = accG;
                    }
                }
                __syncthreads();
            }

            // t2 slice: 8 sub-lanes per (s,a4)
            if (q < S * 4) {
                const int s = q >> 2, a4 = q & 3, a = ch * 4 + a4;
                float M = maxM(lds + R_BMX, w, s);
                float t2;
                if (w == 1) {
                    float acc = 0.f;
                    #pragma unroll
                    for (int j = 0; j < 8; ++j) {
                        int r = lane8 * 8 + j;
                        acc = fmaf(lds[R_ELT + r * 29 + (s + 1)],
                                   lds[R_F2 + (r * 29 + s) * 4 + a4], acc);
                    }
                    t2 = acc;
                } else {
                    const float* tri = lds + R_TRI;
                    const int b1o = off32(w - 1, n);
                    const int r0 = lane8 * 4;
                    float4 tv = *(const float4*)&tri[(b1o + s + 1) * 32 + r0];
                    float aTN = tv.x * lds[R_F + ((r0 + 0) * 29 + s) * 4 + a4]
                              + tv.y * lds[R_F + ((r0 + 1) * 29 + s) * 4 + a4]
                              + tv.z * lds[R_F + ((r0 + 2) * 29 + s) * 4 + a4]
                              + tv.w * lds[R_F + ((r0 + 3) * 29 + s) * 4 + a4];
                    float4 lv = *(const float4*)&tri[(b1o + s) * 32 + r0];
                    float aNT = lv.x * lds[R_G + ((r0 + 0) * 29 + s + w) * 4 + a4]
                              + lv.y * lds[R_G + ((r0 + 1) * 29 + s + w) * 4 + a4]
                              + lv.z * lds[R_G + ((r0 + 2) * 29 + s + w) * 4 + a4]
                              + lv.w * lds[R_G + ((r0 + 3) * 29 + s + w) * 4 + a4];
                    float g0 = __expf(lds[R_BMX + s] +
                                      lds[R_BMX + (w - 1) * NMAX + s + 1] - M);
                    float gw = __expf(lds[R_BMX + (w - 1) * NMAX + s] +
                                      lds[R_BMX + s + w] - M);
                    t2 = aTN * g0 + aNT * gw;
                    if (w >= 3) {
                        const int b2o = off32(w - 2, n);
                        float4 rv = *(const float4*)&tri[(b2o + s + 2) * 32 + r0];
                        float e1 = rv.x * lds[R_F2 + ((r0 + 0) * 29 + s) * 4 + a4]
                                 + rv.y * lds[R_F2 + ((r0 + 1) * 29 + s) * 4 + a4]
                                 + rv.z * lds[R_F2 + ((r0 + 2) * 29 + s) * 4 + a4]
                                 + rv.w * lds[R_F2 + ((r0 + 3) * 29 + s) * 4 + a4];
                        float g1 = __expf(lds[R_BMX + NMAX + s] +
                                          lds[R_BMX + (w - 2) * NMAX + s + 2] - M);
                        t2 = fmaf(e1, g1, t2);
                        if (w >= 4) {
                            float4 l2 = *(const float4*)&tri[(b2o + s) * 32 + r0];
                            float e2 = l2.x * lds[R_G2 + ((r0 + 0) * 29 + s + w - 1) * 4 + a4]
                                     + l2.y * lds[R_G2 + ((r0 + 1) * 29 + s + w - 1) * 4 + a4]
                                     + l2.z * lds[R_G2 + ((r0 + 2) * 29 + s + w - 1) * 4 + a4]
                                     + l2.w * lds[R_G2 + ((r0 + 3) * 29 + s + w - 1) * 4 + a4];
                            float g2 = __expf(lds[R_BMX + (w - 2) * NMAX + s] +
                                              lds[R_BMX + NMAX + s + w - 1] - M);
                            t2 = fmaf(e2, g2, t2);
                        }
                    }
                    if (w >= 5) {
                        float Mc = maxMc(lds + R_BMX, w, s);
                        t2 = fmaf(crPre, __expf(Mc - M), t2);
                    }
                }
                t2 += __shfl_xor(t2, 1, 8);
                t2 += __shfl_xor(t2, 2, 8);
                t2 += __shfl_xor(t2, 4, 8);
                if (lane8 == 0)
                    gstore(rT + (size_t)(w & 7) * SLOTT + s * 32 + a, t2);
            }
            __syncthreads();
            if (tid == 0) gstoreu(&fl[ch], (unsigned)w);
        }

        // epilogue (ch==0): width n-1 span 0 + root logsumexp
        if (ch == 0) {
            if (tid < 64) {
                unsigned tgt = (unsigned)(n - 1);
                for (;;) {
                    unsigned v = (tid < 8) ? gloadu(&fl[tid]) : tgt;
                    if (__ballot(v < tgt) == 0ull) break;
                    __builtin_amdgcn_s_sleep(1);
                }
            }
            __syncthreads();
            if (tid < 32) {
                float qv = gload(rT + (size_t)((n - 1) & 7) * SLOTT + tid);
                float v = qv * __expf(root[b * 32 + tid]);
                for (int off = 16; off > 0; off >>= 1) v += __shfl_xor(v, off, 32);
                if (tid == 0) out[b] = maxM(lds + R_BMX, n - 1, 0) + __logf(v);
            }
        }
    } else {
        // =============== core role (parity group, 256-col slice) ===============
        const int idx = ch - 8, slice = idx & 3, par = idx >> 2;
        float4 e4a, e4b;
        {
            int g = tid >> 5, a = tid & 31;
            e4a = *(const float4*)(ENc_g + ((size_t)(b * 256 + slice * 64 + g * 2) * 32 + a) * 4);
            e4b = *(const float4*)(ENc_g + ((size_t)(b * 256 + slice * 64 + g * 2 + 1) * 32 + a) * 4);
        }
        if (tid < n) lds[C_BMX + tid] = bmax0_g[b * 32 + tid];
        __syncthreads();
        int lastFin = 0;
        const int W0 = (par == 1) ? 5 : 6;
        for (int W = W0; W < n; W += 2) {
            const int S = n - W, Sp2 = S | 1;
            const int cnt = W - 4;
            int q4 = (cnt + 3) >> 2; if (!(q4 & 1)) ++q4;
            const int K4 = 4 * q4;
            // spin: row flags >= W-3
            if (tid < 64) {
                unsigned tgt = (unsigned)(W - 3);
                for (;;) {
                    unsigned v = (tid < 8) ? gloadu(&fl[tid]) : tgt;
                    if (__ballot(v < tgt) == 0ull) break;
                    __builtin_amdgcn_s_sleep(1);
                }
            }
            __syncthreads();

            // finalize rows lastFin+1..W-3 (prefetch all ring loads first)
            {
                const int nf = (W - 3) - lastFin;   // <= 3
                float qv[3];
                for (int i = 0; i < nf; ++i) {
                    int wf = lastFin + 1 + i;
                    qv[i] = (tid < (n - wf) * 32)
                        ? gload(rT + (size_t)(wf & 7) * SLOTT + tid) : 0.f;
                }
                for (int i = 0; i < nf; ++i) {
                    int wf = lastFin + 1 + i;
                    if (tid < (n - wf) * 32) {
                        int s = tid >> 5, aa = tid & 31;
                        float m2 = qv[i];
                        for (int off = 16; off > 0; off >>= 1)
                            m2 = fmaxf(m2, __shfl_xor(m2, off, 32));
                        lds[C_TRI + (off32(wf, n) + s) * 32 + aa] = qv[i] / m2;
                        if (aa == 0)
                            lds[C_BMX + wf * NMAX + s] =
                                __logf(m2) + maxM(lds + C_BMX, wf, s);
                    }
                    __syncthreads();
                }
                lastFin = W - 3;
            }

            // A3 (A2 fused): k-packed ELK/ERK, g folded into ERK
            if (tid < S * 32) {
                int s = tid >> 5, sym = tid & 31;
                float Mc = maxMc(lds + C_BMX, W, s);
                int eo = (sym * Sp2 + s) * K4;
                for (int k = 2; k <= W - 3; ++k)
                    lds[C_ERK + eo + k - 2] =
                        lds[C_TRI + (off32(W - 1 - k, n) + s + k + 1) * 32 + sym] *
                        __expf(lds[C_BMX + k * NMAX + s] +
                               lds[C_BMX + (W - 1 - k) * NMAX + s + k + 1] - Mc);
                for (int j2 = cnt; j2 < K4; ++j2) lds[C_ERK + eo + j2] = 0.f;
                if (sym < 8) {
                    int lo = (sym * Sp2 + s) * K4;
                    int gl = slice * 8 + sym;
                    for (int k = 2; k <= W - 3; ++k)
                        lds[C_ELK + lo + k - 2] =
                            lds[C_TRI + (off32(k, n) + s) * 32 + gl];
                    for (int j2 = cnt; j2 < K4; ++j2) lds[C_ELK + lo + j2] = 0.f;
                }
            }
            __syncthreads();

            // C: numer (256 cols) -> bf16
            {
                int cL = tid & 255, sh = tid >> 8;
                int lloc = cL >> 5, r = cL & 31;
                unsigned short* np = (unsigned short*)(lds + C_NUM);
                for (int s = sh; s < S; s += 4) {
                    const float* ep = lds + C_ELK + (lloc * Sp2 + s) * K4;
                    const float* rp = lds + C_ERK + (r * Sp2 + s) * K4;
                    float acc = 0.f;
                    for (int j = 0; j < K4; j += 4)
                        acc = dot4acc(*(const float4*)(ep + j),
                                      *(const float4*)(rp + j), acc);
                    np[s * 260 + cL] = f2b(acc);
                }
            }
            __syncthreads();

            // D: contract vs E regs (2 c4/thread), wave-pair reduce -> bf16 RED
            {
                const unsigned short* np = (const unsigned short*)(lds + C_NUM);
                unsigned short* red = (unsigned short*)(lds + C_RED);
                int g = tid >> 5, a = tid & 31, wv = tid >> 6;
                bool low = (tid & 32) == 0;
                for (int s = 0; s < S; ++s) {
                    const unsigned short* pp = np + s * 260 + g * 8;
                    uint2 u0 = *(const uint2*)pp;
                    uint2 u1 = *(const uint2*)(pp + 4);
                    #define LOu(x) __uint_as_float((x) << 16)
                    #define HIu(x) __uint_as_float((x) & 0xffff0000u)
                    float acc = LOu(u0.x) * e4a.x + HIu(u0.x) * e4a.y
                              + LOu(u0.y) * e4a.z + HIu(u0.y) * e4a.w
                              + LOu(u1.x) * e4b.x + HIu(u1.x) * e4b.y
                              + LOu(u1.y) * e4b.z + HIu(u1.y) * e4b.w;
                    #undef LOu
                    #undef HIu
                    acc += __shfl_xor(acc, 32, 64);
                    if (low) red[wv * 896 + s * 32 + a] = f2b(acc);
                }
            }
            __syncthreads();

            // E: 16-group reduce -> publish slice partial
            if (tid < S * 32) {
                const unsigned short* red = (const unsigned short*)(lds + C_RED);
                float t = 0.f;
                for (int g2 = 0; g2 < 16; ++g2) t += b2f(red[g2 * 896 + tid]);
                gstore(rN + (size_t)(W & 3) * SLOTN + (size_t)tid * 4 + slice, t);
            }
            __syncthreads();
            if (tid == 0) gstoreu(&fl[ch], (unsigned)W);
        }
    }
}

extern "C" void kernel_launch(void* const* d_in, const int* in_sizes, int n_in,
                              void* d_out, int out_size, void* d_ws, size_t ws_size,
                              hipStream_t stream) {
    const float* unary = (const float*)d_in[0]; // B,n,64
    const float* rule  = (const float*)d_in[1]; // B,32,96,96
    const float* root  = (const float*)d_in[2]; // B,32
    float* out = (float*)d_out;

    const int B = in_sizes[2] / 32;
    int n = in_sizes[0] / (B * 64);

    float* ws = (float*)d_ws;
    float* elT_g = ws;                                  // B*64*n
    float* bmax0 = elT_g + (size_t)B * 64 * n;          // B*32
    float* H_g   = bmax0 + (size_t)B * 32;              // B*8*7424
    float* F_g   = H_g + (size_t)B * 8 * 7424;          // B*8*3712
    float* G_g   = F_g + (size_t)B * 8 * 3712;          // B*8*3712
    float* ENa_g = G_g + (size_t)B * 8 * 3712;          // B*8*4096
    float* ENc_g = ENa_g + (size_t)B * 8 * 4096;        // B*32768
    float* ringT = ENc_g + (size_t)B * 32768;           // B*8*SLOTT
    float* ringN = ringT + (size_t)B * 8 * SLOTT;       // B*4*SLOTN
    unsigned* flags = (unsigned*)(ringN + (size_t)B * 4 * SLOTN); // B*32

    prep_kernel<<<dim3(B), 256, 0, stream>>>(unary, elT_g, bmax0, flags, n);

    const int packLds = (9216 + 64 * n) * 4;
    hipFuncSetAttribute((const void*)pack_kernel,
                        hipFuncAttributeMaxDynamicSharedMemorySize, packLds);
    pack_kernel<<<dim3(32, B), 256, packLds, stream>>>(rule, elT_g, H_g, F_g,
                                                       G_g, ENa_g, ENc_g, n);

    hipFuncSetAttribute((const void*)inside_kernel,
                        hipFuncAttributeMaxDynamicSharedMemorySize, LDSF * 4);
    void* args[] = {
        (void*)&elT_g, (void*)&bmax0, (void*)&H_g, (void*)&F_g, (void*)&G_g,
        (void*)&ENa_g, (void*)&ENc_g, (void*)&ringT, (void*)&ringN,
        (void*)&root, (void*)&out, (void*)&flags, (void*)&n
    };
    hipLaunchCooperativeKernel((void*)inside_kernel, dim3(B * 16), dim3(1024),
                               args, LDSF * 4, stream);
}